// Round 2
// baseline (21733.971 us; speedup 1.0000x reference)
//
#include <hip/hip_runtime.h>
#include <stdint.h>

// CharRNN MI355X — persistent-RNN design, small-workspace edition.
//   K1 k_prep : proj[v][h] = embedding[v,:] @ W_ih + b_h  (VOCAB=64 table)
//   K2 k_rnn  : persistent 256 blocks (1/CU). Block (gi,gj): batch rows
//               gi*32..+32, hidden cols gj*32..+32. W_hh slice bf16 in LDS.
//               Per step: MFMA(h_prev @ Whh_slice) + tanh, h_t -> 16-slot
//               global ring, per-group(32 blocks) counter barrier, restage.
//               Every 16 steps: chunked logits MFMA (block = 16 rows x 1 t
//               x 64 voc; W_ho frags in 128 VGPRs/wave) -> d_out directly.
// d_ws: proj f32 @0 (256KB) | cnt @262144 (1KB) | ring bf16 @1MB (16MB)
// Total ws need ~18 MB (vs 258 MB in the crashed version).

#define BATCH 256
#define SEQ   512
#define HID   1024
#define VOC   64
#define EMB   256
#define FINAL_OFF (BATCH * SEQ * VOC)   // 8388608
#define RING_SLOTS 16

typedef __attribute__((ext_vector_type(8))) short short8;
typedef __attribute__((ext_vector_type(4))) float f32x4;

__device__ inline unsigned short f2bf(float f) {
  union { float f; unsigned u; } v; v.f = f;
  unsigned u = v.u;
  return (unsigned short)((u + 0x7FFFu + ((u >> 16) & 1u)) >> 16);  // RNE
}

// ---------------- K1: projection table -------------------------------------
__global__ __launch_bounds__(256) void k_prep(const float* __restrict__ emb,
                                              const float* __restrict__ Wih,
                                              const float* __restrict__ bh,
                                              float* __restrict__ proj) {
  __shared__ float es[EMB];
  const int v = blockIdx.x >> 2;        // 0..63
  const int p = blockIdx.x & 3;         // h-quarter
  const int tid = threadIdx.x;
  es[tid] = emb[v * EMB + tid];
  __syncthreads();
  const int h = p * 256 + tid;
  float acc = bh[h];
  for (int e = 0; e < EMB; ++e) acc += es[e] * Wih[e * HID + h];
  proj[v * HID + h] = acc;
}

// ---------------- group barrier --------------------------------------------
__device__ inline void group_barrier(unsigned int* cnt_i, int tid, int round) {
  __threadfence();                       // release h_t stores (agent scope)
  __syncthreads();
  if (tid == 0) {
    atomicAdd(cnt_i, 1u);
    int guard = 0;
    while (__hip_atomic_load(cnt_i, __ATOMIC_RELAXED, __HIP_MEMORY_SCOPE_AGENT)
           < 32u * (unsigned)round) {
      __builtin_amdgcn_s_sleep(2);
      if (++guard > (1 << 17)) break;    // bailout: wrong answer beats a hang
    }
  }
  __syncthreads();
  __threadfence();                       // acquire: drop stale cached h
}

// ---------------- K2: persistent recurrence + inline logits ----------------
// LDS: w_lds 65536 | h_lds 66048 (32 rows x 2064B) | p_lds 8192 | xs 128
__global__ __launch_bounds__(256, 1) void k_rnn(
    const int* __restrict__ x, const float* __restrict__ Whh,
    const float* __restrict__ proj, const float* __restrict__ Who,
    const float* __restrict__ bo, unsigned short* __restrict__ ring,
    float* __restrict__ out, float* __restrict__ final_out,
    unsigned int* __restrict__ cnt) {
  extern __shared__ char smem[];
  unsigned short* w_lds = (unsigned short*)smem;            // 65536
  char*           h_lds = smem + 65536;                     // 66048
  float*          p_lds = (float*)(smem + 131584);          // 8192
  int*            xs    = (int*)(smem + 139776);            // 128

  const int tid = threadIdx.x, bid = blockIdx.x;
  const int gi = bid & 7, gj = bid >> 3;                    // group / col-slice
  const int row0 = gi * 32;
  const int lane = tid & 63, wv = tid >> 6;
  const int mt = wv & 1, nt = wv >> 1;                      // recurrence tiles
  const int l15 = lane & 15, q = lane >> 4;

  // W_hh column slice -> LDS bf16 B-fragment order (once).
  for (int it = 0; it < 128; ++it) {
    int u = it * 256 + tid;
    int n = u & 31, j8 = (u >> 5) & 7, qq = (u >> 8) & 3, kb = u >> 10;
    w_lds[((kb * 4 + qq) * 32 + n) * 8 + j8] =
        f2bf(Whh[(kb * 32 + qq * 8 + j8) * HID + gj * 32 + n]);
  }
  // proj slice [64 vocab][32 cols] -> LDS f32 (once).
  for (int it = 0; it < 8; ++it) {
    int u = it * 256 + tid;
    p_lds[u] = proj[(u >> 5) * HID + gj * 32 + (u & 31)];
  }
  if (tid < 32) xs[tid] = x[(row0 + tid) * SEQ];
  // W_ho B-fragments for this wave's 16-voc tile -> registers (128 VGPRs).
  short8 wf[32];
  #pragma unroll
  for (int kb = 0; kb < 32; ++kb) {
    short8 v8;
    #pragma unroll
    for (int j = 0; j < 8; ++j)
      v8[j] = (short)f2bf(Who[(kb * 32 + q * 8 + j) * VOC + wv * 16 + l15]);
    wf[kb] = v8;
  }
  __syncthreads();

  unsigned int* cnt_i = cnt + gi * 32;                      // 128B-strided
  const int hcol = gj * 32 + nt * 16 + l15;
  const char* abase = h_lds + (mt * 16 + l15) * 2064 + q * 16;
  const char* bbase = (const char*)w_lds + (q * 32 + nt * 16 + l15) * 16;
  const float bias = bo[wv * 16 + l15];
  int round = 0;

  for (int t = 0; t < SEQ; ++t) {
    // 1) recurrence MFMA: 32x32 tile = h_prev(32x1024) @ Whh_slice(1024x32)
    f32x4 a0 = {0.f, 0.f, 0.f, 0.f}, a1 = {0.f, 0.f, 0.f, 0.f};
    if (t > 0) {
      #pragma unroll 4
      for (int kb = 0; kb < 32; kb += 2) {
        short8 af0 = *(const short8*)(abase + kb * 64);
        short8 bf0 = *(const short8*)(bbase + kb * 2048);
        a0 = __builtin_amdgcn_mfma_f32_16x16x32_bf16(af0, bf0, a0, 0, 0, 0);
        short8 af1 = *(const short8*)(abase + kb * 64 + 64);
        short8 bf1 = *(const short8*)(bbase + kb * 2048 + 2048);
        a1 = __builtin_amdgcn_mfma_f32_16x16x32_bf16(af1, bf1, a1, 0, 0, 0);
      }
    }
    // 2) epilogue: h_t = tanh(proj[x_t] + acc) -> ring slot (bf16)
    unsigned short* slot = ring + (size_t)(t & (RING_SLOTS - 1)) * (BATCH * HID);
    #pragma unroll
    for (int r = 0; r < 4; ++r) {
      int ml = mt * 16 + q * 4 + r;                         // D row = q*4+r
      int b  = row0 + ml;
      float hv = tanhf(p_lds[xs[ml] * 32 + nt * 16 + l15] + a0[r] + a1[r]);
      slot[b * HID + hcol] = f2bf(hv);
      if (t == SEQ - 1) final_out[b * HID + hcol] = hv;
    }
    // 3) publish + group barrier
    ++round;
    group_barrier(cnt_i, tid, round);
    // 4) chunked logits every 16 steps: this block does 16 rows x 1 t x 64 v
    if ((t & 15) == 15) {
      int tsel  = (t - 15) + (gj >> 1);
      int rbase = row0 + (gj & 1) * 16;
      const unsigned short* hs =
          ring + (size_t)(tsel & (RING_SLOTS - 1)) * (BATCH * HID) +
          (size_t)(rbase + l15) * HID + q * 8;              // A[m=l15][k=q*8+j]
      f32x4 lc = {0.f, 0.f, 0.f, 0.f};
      #pragma unroll
      for (int kb = 0; kb < 32; ++kb) {
        short8 af = *(const short8*)(hs + kb * 32);
        lc = __builtin_amdgcn_mfma_f32_16x16x32_bf16(af, wf[kb], lc, 0, 0, 0);
      }
      #pragma unroll
      for (int rr = 0; rr < 4; ++rr) {
        int b = rbase + q * 4 + rr;
        out[((size_t)b * SEQ + tsel) * VOC + wv * 16 + l15] = lc[rr] + bias;
      }
      if (t != SEQ - 1) {                 // protect ring reuse at t+1
        ++round;
        group_barrier(cnt_i, tid, round);
      }
    }
    // 5) restage h_t (full 32 rows x 1024) -> h_lds for next step's A-frags
    if (t < SEQ - 1) {
      #pragma unroll
      for (int rr = 0; rr < 16; ++rr) {
        int flat = rr * 2048 + tid * 8;
        int m = flat >> 10, k = flat & 1023;
        uint4 vv = *(const uint4*)(slot + (row0 + m) * HID + k);
        *(uint4*)(h_lds + m * 2064 + k * 2) = vv;
      }
      if (tid < 32) xs[tid] = x[(row0 + tid) * SEQ + (t + 1)];
      __syncthreads();
    }
  }
}

// ---------------- launch ----------------------------------------------------
extern "C" void kernel_launch(void* const* d_in, const int* in_sizes, int n_in,
                              void* d_out, int out_size, void* d_ws, size_t ws_size,
                              hipStream_t stream) {
  const int*   x   = (const int*)d_in[0];
  const float* emb = (const float*)d_in[1];
  const float* Wih = (const float*)d_in[2];
  const float* Whh = (const float*)d_in[3];
  const float* bh  = (const float*)d_in[4];
  const float* Who = (const float*)d_in[5];
  const float* bo  = (const float*)d_in[6];
  float* out = (float*)d_out;

  char* ws = (char*)d_ws;
  float*          proj = (float*)ws;                         // 262144 B
  unsigned int*   cnt  = (unsigned int*)(ws + 262144);       // 1024 B
  unsigned short* ring = (unsigned short*)(ws + (1 << 20));  // 16 MiB

  size_t need = (size_t)(1 << 20) + (size_t)RING_SLOTS * BATCH * HID * 2;
  if (ws_size < need) return;  // diagnostic fail (absmax) instead of a fault

  (void)hipFuncSetAttribute(reinterpret_cast<const void*>(k_rnn),
                            hipFuncAttributeMaxDynamicSharedMemorySize, 139904);

  k_prep<<<256, 256, 0, stream>>>(emb, Wih, bh, proj);
  hipMemsetAsync(cnt, 0, 1024, stream);
  k_rnn<<<256, 256, 139904, stream>>>(x, Whh, proj, Who, bo, ring,
                                      out, out + FINAL_OFF, cnt);
}

// Round 4
// 2210.675 us; speedup vs baseline: 9.8314x; 9.8314x over previous
//
#include <hip/hip_runtime.h>
#include <stdint.h>

// CharRNN MI355X — persistent-RNN, builtin-only coherent-exchange edition.
//   K1 k_prep : proj[v][h] = embedding[v,:] @ W_ih + b_h  (VOCAB=64 table)
//   K2 k_rnn  : persistent 256 blocks (1/CU). Block (gi,gj): batch rows
//               gi*32..+32, hidden cols gj*32..+32. W_hh slice bf16 in LDS.
//               Cross-block h exchange via relaxed AGENT-scope atomic
//               loads/stores (per-access coherent, no cache-maintenance
//               fences — round 2's __threadfence L2 walks were ~39us/barrier).
//               Release ordering is __syncthreads()' own vmcnt(0) drain.
//               Every 16 steps: chunked logits MFMA (block = 16 rows x 1 t
//               x 64 voc) -> d_out directly. 32-slot ring -> no reuse barrier.
// d_ws: proj f32 @0 (256KB) | cnt @262144 (1KB) | ring bf16 @1MB (16MB)

#define BATCH 256
#define SEQ   512
#define HID   1024
#define VOC   64
#define EMB   256
#define FINAL_OFF (BATCH * SEQ * VOC)   // 8388608
#define RING_SLOTS 32

typedef __attribute__((ext_vector_type(8))) short short8;
typedef __attribute__((ext_vector_type(4))) float f32x4;
typedef unsigned long long u64;

__device__ inline unsigned short f2bf(float f) {
  union { float f; unsigned u; } v; v.f = f;
  unsigned u = v.u;
  return (unsigned short)((u + 0x7FFFu + ((u >> 16) & 1u)) >> 16);  // RNE
}

// coherent 8B load (agent scope, relaxed) — global_load_dwordx2 w/ coherence
// bits; sees other XCDs' stores without any cache-maintenance fence.
__device__ inline u64 cload64(const unsigned short* p) {
  return __hip_atomic_load((const u64*)p, __ATOMIC_RELAXED,
                           __HIP_MEMORY_SCOPE_AGENT);
}
__device__ inline void cstore32(unsigned short* p, unsigned v) {
  __hip_atomic_store((unsigned*)p, v, __ATOMIC_RELAXED,
                     __HIP_MEMORY_SCOPE_AGENT);
}

// ---------------- K1: projection table -------------------------------------
__global__ __launch_bounds__(256) void k_prep(const float* __restrict__ emb,
                                              const float* __restrict__ Wih,
                                              const float* __restrict__ bh,
                                              float* __restrict__ proj) {
  __shared__ float es[EMB];
  const int v = blockIdx.x >> 2;        // 0..63
  const int p = blockIdx.x & 3;         // h-quarter
  const int tid = threadIdx.x;
  es[tid] = emb[v * EMB + tid];
  __syncthreads();
  const int h = p * 256 + tid;
  float acc = bh[h];
  for (int e = 0; e < EMB; ++e) acc += es[e] * Wih[e * HID + h];
  proj[v * HID + h] = acc;
}

// ---------------- group barrier (no cache-maintenance fences) ---------------
// __syncthreads() lowers to s_waitcnt vmcnt(0) lgkmcnt(0) + s_barrier, which
// drains this block's coherent data stores to the mall = release. Poll side
// reads fresh data because all cross-block loads are per-access coherent.
__device__ inline void group_barrier(unsigned int* cnt_i, int tid, int round) {
  __syncthreads();
  if (tid == 0) {
    atomicAdd(cnt_i, 1u);
    int guard = 0;
    while (__hip_atomic_load(cnt_i, __ATOMIC_RELAXED, __HIP_MEMORY_SCOPE_AGENT)
           < 32u * (unsigned)round) {
      __builtin_amdgcn_s_sleep(1);
      if (++guard > (1 << 16)) break;    // bailout: wrong answer beats a hang
    }
  }
  __syncthreads();
}

// ---------------- K2: persistent recurrence + inline logits ----------------
// LDS: w_lds 65536 | h_lds 66048 (32 rows x 2064B) | p_lds 8192 | xs 128
__global__ __launch_bounds__(256, 1) void k_rnn(
    const int* __restrict__ x, const float* __restrict__ Whh,
    const float* __restrict__ proj, const float* __restrict__ Who,
    const float* __restrict__ bo, unsigned short* __restrict__ ring,
    float* __restrict__ out, float* __restrict__ final_out,
    unsigned int* __restrict__ cnt) {
  extern __shared__ char smem[];
  unsigned short* w_lds = (unsigned short*)smem;            // 65536
  char*           h_lds = smem + 65536;                     // 66048
  float*          p_lds = (float*)(smem + 131584);          // 8192
  int*            xs    = (int*)(smem + 139776);            // 128

  const int tid = threadIdx.x, bid = blockIdx.x;
  const int gi = bid & 7, gj = bid >> 3;                    // group / col-slice
  const int row0 = gi * 32;
  const int lane = tid & 63, wv = tid >> 6;
  const int mt = wv & 1, nt = wv >> 1;                      // recurrence tiles
  const int l15 = lane & 15, q = lane >> 4;

  // W_hh column slice -> LDS bf16 B-fragment order (once).
  for (int it = 0; it < 128; ++it) {
    int u = it * 256 + tid;
    int n = u & 31, j8 = (u >> 5) & 7, qq = (u >> 8) & 3, kb = u >> 10;
    w_lds[((kb * 4 + qq) * 32 + n) * 8 + j8] =
        f2bf(Whh[(kb * 32 + qq * 8 + j8) * HID + gj * 32 + n]);
  }
  // proj slice [64 vocab][32 cols] -> LDS f32 (once).
  for (int it = 0; it < 8; ++it) {
    int u = it * 256 + tid;
    p_lds[u] = proj[(u >> 5) * HID + gj * 32 + (u & 31)];
  }
  if (tid < 32) xs[tid] = x[(row0 + tid) * SEQ];
  // W_ho B-fragments for this wave's 16-voc tile (compiler may rematerialize).
  short8 wf[32];
  #pragma unroll
  for (int kb = 0; kb < 32; ++kb) {
    short8 v8;
    #pragma unroll
    for (int j = 0; j < 8; ++j)
      v8[j] = (short)f2bf(Who[(kb * 32 + q * 8 + j) * VOC + wv * 16 + l15]);
    wf[kb] = v8;
  }
  __syncthreads();

  unsigned int* cnt_i = cnt + gi * 32;                      // 128B-strided
  const int hcol = gj * 32 + nt * 16 + l15;
  const char* abase = h_lds + (mt * 16 + l15) * 2064 + q * 16;
  const char* bbase = (const char*)w_lds + (q * 32 + nt * 16 + l15) * 16;
  const float bias = bo[wv * 16 + l15];

  for (int t = 0; t < SEQ; ++t) {
    // 1) recurrence MFMA: 32x32 tile = h_prev(32x1024) @ Whh_slice(1024x32)
    f32x4 a0 = {0.f, 0.f, 0.f, 0.f}, a1 = {0.f, 0.f, 0.f, 0.f};
    if (t > 0) {
      #pragma unroll 4
      for (int kb = 0; kb < 32; kb += 2) {
        short8 af0 = *(const short8*)(abase + kb * 64);
        short8 bf0 = *(const short8*)(bbase + kb * 2048);
        a0 = __builtin_amdgcn_mfma_f32_16x16x32_bf16(af0, bf0, a0, 0, 0, 0);
        short8 af1 = *(const short8*)(abase + kb * 64 + 64);
        short8 bf1 = *(const short8*)(bbase + kb * 2048 + 2048);
        a1 = __builtin_amdgcn_mfma_f32_16x16x32_bf16(af1, bf1, a1, 0, 0, 0);
      }
    }
    // 2) epilogue: h_t = tanh(proj[x_t] + acc); publish packed col-pairs via
    //    coherent dword stores (even l15 lanes store).
    unsigned short* slot = ring + (size_t)(t & (RING_SLOTS - 1)) * (BATCH * HID);
    float hv[4];
    #pragma unroll
    for (int r = 0; r < 4; ++r) {
      int ml = mt * 16 + q * 4 + r;                         // D row = q*4+r
      hv[r] = tanhf(p_lds[xs[ml] * 32 + nt * 16 + l15] + a0[r] + a1[r]);
      if (t == SEQ - 1) final_out[(row0 + ml) * HID + hcol] = hv[r];
    }
    #pragma unroll
    for (int r = 0; r < 4; ++r) {
      unsigned myb = f2bf(hv[r]);
      unsigned oth = (unsigned)__shfl_xor((int)myb, 1);
      if ((l15 & 1) == 0) {
        int b = row0 + mt * 16 + q * 4 + r;
        cstore32(slot + (size_t)b * HID + hcol, myb | (oth << 16));
      }
    }
    // 3) group barrier (release = __syncthreads' vmcnt(0) drain)
    group_barrier(cnt_i, tid, t + 1);
    // 4) chunked logits every 16 steps: this block does 16 rows x 1 t x 64 v
    if ((t & 15) == 15) {
      int tsel  = (t - 15) + (gj >> 1);
      int rbase = row0 + (gj & 1) * 16;
      const unsigned short* hs =
          ring + (size_t)(tsel & (RING_SLOTS - 1)) * (BATCH * HID) +
          (size_t)(rbase + l15) * HID;                      // A row base
      f32x4 lc = {0.f, 0.f, 0.f, 0.f};
      for (int g = 0; g < 4; ++g) {
        u64 hb[16];
        #pragma unroll
        for (int j = 0; j < 8; ++j) {
          const unsigned short* pk = hs + (g * 8 + j) * 32 + q * 8;
          hb[2 * j]     = cload64(pk);
          hb[2 * j + 1] = cload64(pk + 4);
        }
        #pragma unroll
        for (int j = 0; j < 8; ++j) {
          union { u64 d[2]; short8 s; } c;
          c.d[0] = hb[2 * j]; c.d[1] = hb[2 * j + 1];
          lc = __builtin_amdgcn_mfma_f32_16x16x32_bf16(c.s, wf[g * 8 + j],
                                                       lc, 0, 0, 0);
        }
      }
      #pragma unroll
      for (int rr = 0; rr < 4; ++rr) {
        int b = rbase + q * 4 + rr;
        out[((size_t)b * SEQ + tsel) * VOC + wv * 16 + l15] = lc[rr] + bias;
      }
      // no reuse barrier needed: 32-slot ring, reuse is >=16 barriers away
    }
    // 5) restage h_t (32 rows x 1024, coherent 8B loads) -> h_lds
    if (t < SEQ - 1) {
      u64 tmp[32];
      #pragma unroll
      for (int rr = 0; rr < 32; ++rr)
        tmp[rr] = cload64(slot + (size_t)(row0 + rr) * HID + tid * 4);
      #pragma unroll
      for (int rr = 0; rr < 32; ++rr)
        *(u64*)(h_lds + rr * 2064 + tid * 8) = tmp[rr];
      if (tid < 32) xs[tid] = x[(row0 + tid) * SEQ + (t + 1)];
      __syncthreads();
    }
  }
}

// ---------------- launch ----------------------------------------------------
extern "C" void kernel_launch(void* const* d_in, const int* in_sizes, int n_in,
                              void* d_out, int out_size, void* d_ws, size_t ws_size,
                              hipStream_t stream) {
  const int*   x   = (const int*)d_in[0];
  const float* emb = (const float*)d_in[1];
  const float* Wih = (const float*)d_in[2];
  const float* Whh = (const float*)d_in[3];
  const float* bh  = (const float*)d_in[4];
  const float* Who = (const float*)d_in[5];
  const float* bo  = (const float*)d_in[6];
  float* out = (float*)d_out;

  char* ws = (char*)d_ws;
  float*          proj = (float*)ws;                         // 262144 B
  unsigned int*   cnt  = (unsigned int*)(ws + 262144);       // 1024 B
  unsigned short* ring = (unsigned short*)(ws + (1 << 20));  // 16 MiB

  size_t need = (size_t)(1 << 20) + (size_t)RING_SLOTS * BATCH * HID * 2;
  if (ws_size < need) return;  // diagnostic fail (absmax) instead of a fault

  (void)hipFuncSetAttribute(reinterpret_cast<const void*>(k_rnn),
                            hipFuncAttributeMaxDynamicSharedMemorySize, 139904);

  k_prep<<<256, 256, 0, stream>>>(emb, Wih, bh, proj);
  hipMemsetAsync(cnt, 0, 1024, stream);
  k_rnn<<<256, 256, 139904, stream>>>(x, Whh, proj, Who, bo, ring,
                                      out, out + FINAL_OFF, cnt);
}